// Round 11
// baseline (239.538 us; speedup 1.0000x reference)
//
#include <hip/hip_runtime.h>
#include <math.h>

typedef float v2f __attribute__((ext_vector_type(2)));
#define FMA2(a, b, c) __builtin_elementwise_fma((a), (b), (c))
#define WAVE_SYNC() asm volatile("s_waitcnt lgkmcnt(0)" ::: "memory")

// ================= Kernel A: conv1+conv2+conv3+pool fused, one block per image =================
// R21 = R17..R20 convpool byte-identical (62us anchor at normal clocks; R20's 73-76 read as
//  clock variance -- recheck). Head: FC1+quantum verbatim (2 block barriers), then PER-WAVE MLP:
//  wave wv owns image wv end-to-end; z is already in-register post-butterfly (no zbuf); lane l
//  computes outputs l,l+64,.. into a wave-private 512-float LDS strip with wave-synchronous
//  lgkmcnt fences (no block barriers). Per-output scalar FMA order unchanged -> bitwise same.
__global__ __launch_bounds__(256, 8)
void convpool_kernel(const float* __restrict__ x,
                     const float* __restrict__ w1, const float* __restrict__ b1,
                     const float* __restrict__ w2, const float* __restrict__ b2,
                     const float* __restrict__ w3, const float* __restrict__ b3,
                     float* __restrict__ poolout)
{
    __shared__ __align__(16) float arena[4648];   // phase A: conv1-out [4][32][36] + zero row @4608
                                                  // phase B: conv2-out [8][18][20] @0 + w3p [16][100] @2880 + b3 @4480
    const int tid  = threadIdx.x;
    const int b    = blockIdx.x;
    const int lane = tid & 63;

    // ---- issue w3 (padded [16][8][12], oc-stride 100) + b3 loads into registers ----
    float wstage[7];
    #pragma unroll
    for (int j = 0; j < 7; j++) {
        const int s  = tid + 256 * j;          // 0..1791, valid slots < 1600
        const int oc = s / 100;
        const int r  = s - oc * 100;
        const int ic = r / 12;
        const int k  = r - ic * 12;
        wstage[j] = (s < 1600 && r < 96 && k < 9) ? w3[oc * 72 + ic * 9 + k] : 0.f;
    }
    const float bstage = (tid < 16) ? b3[tid] : 0.f;

    // ---- zero row for conv2's row -1 (ordered by the post-conv1 barrier) ----
    if (tid < 40) arena[4608 + tid] = 0.f;

    // ---- conv1: k5 s2 p2, oc-packed: aP[px][{oc0,oc1}|{oc2,oc3}] ----
    {
        const float* xb = x + (size_t)b * 4096;
        const int oh  = tid >> 3;              // 0..31
        const int ow  = tid & 7;               // output block index (4 cols)
        const int ow0 = ow * 4;
        const int c0  = ow0 * 2 - 2;
        const bool cmL = (ow == 0);
        const bool cmR = (ow == 7);
        v2f aP[4][2];                           // [px][ocpair]
        {
            const v2f b01 = {b1[0], b1[1]};
            const v2f b23 = {b1[2], b1[3]};
            #pragma unroll
            for (int p = 0; p < 4; p++) { aP[p][0] = b01; aP[p][1] = b23; }
        }
        #pragma unroll
        for (int kh = 0; kh < 5; kh++) {
            const int ih = oh * 2 - 2 + kh;
            if (ih >= 0 && ih < 64) {
                const float* row = xb + ih * 64;
                float colv[11];
                {   // edges: clamped addresses, masked values
                    float v0 = row[cmL ? 0 : c0];
                    float v1 = row[cmL ? 0 : c0 + 1];
                    float vA = row[cmR ? 63 : c0 + 10];
                    colv[0]  = cmL ? 0.f : v0;
                    colv[1]  = cmL ? 0.f : v1;
                    colv[10] = cmR ? 0.f : vA;
                }
                {   // middle 8 taps: two aligned dwordx4 (c0+2 = ow*8)
                    const float4 m0 = *(const float4*)(row + c0 + 2);
                    const float4 m1 = *(const float4*)(row + c0 + 6);
                    colv[2] = m0.x; colv[3] = m0.y; colv[4] = m0.z; colv[5] = m0.w;
                    colv[6] = m1.x; colv[7] = m1.y; colv[8] = m1.z; colv[9] = m1.w;
                }
                #pragma unroll
                for (int kw = 0; kw < 5; kw++) {
                    const v2f w01 = {w1[kh * 5 + kw],      w1[25 + kh * 5 + kw]};
                    const v2f w23 = {w1[50 + kh * 5 + kw], w1[75 + kh * 5 + kw]};
                    #pragma unroll
                    for (int p = 0; p < 4; p++) {
                        const float c = colv[kw + 2 * p];
                        const v2f cs = {c, c};          // op_sel broadcast, no movs
                        aP[p][0] = FMA2(cs, w01, aP[p][0]);
                        aP[p][1] = FMA2(cs, w23, aP[p][1]);
                    }
                }
            }
        }
        // store: [4][32][36], block (ow ^ ((oh>>1)&1)) -> conflict-free b128
        const int bsw1 = (oh >> 1) & 1;
        float* obase = arena + oh * 36 + ((ow ^ bsw1) << 2);
        {
            float4 v;
            v.x = fmaxf(aP[0][0].x, 0.f); v.y = fmaxf(aP[1][0].x, 0.f);
            v.z = fmaxf(aP[2][0].x, 0.f); v.w = fmaxf(aP[3][0].x, 0.f);
            *(float4*)(obase) = v;
            v.x = fmaxf(aP[0][0].y, 0.f); v.y = fmaxf(aP[1][0].y, 0.f);
            v.z = fmaxf(aP[2][0].y, 0.f); v.w = fmaxf(aP[3][0].y, 0.f);
            *(float4*)(obase + 1152) = v;
            v.x = fmaxf(aP[0][1].x, 0.f); v.y = fmaxf(aP[1][1].x, 0.f);
            v.z = fmaxf(aP[2][1].x, 0.f); v.w = fmaxf(aP[3][1].x, 0.f);
            *(float4*)(obase + 2304) = v;
            v.x = fmaxf(aP[0][1].y, 0.f); v.y = fmaxf(aP[1][1].y, 0.f);
            v.z = fmaxf(aP[2][1].y, 0.f); v.w = fmaxf(aP[3][1].y, 0.f);
            *(float4*)(obase + 3456) = v;
        }
    }
    __syncthreads();

    // ---- conv2: k3 s2 p1, oc-packed acc[px] = {oc0, oc0+4} ----
    v2f cacc[4];
    {
        const int oc0 = __builtin_amdgcn_readfirstlane(tid >> 6);   // 0..3, wave-uniform
        const int oh  = lane >> 2;             // output row 0..15
        const int w   = lane & 3;              // output col block (4 cols)
        {
            const v2f bb = {b2[oc0], b2[oc0 + 4]};
            #pragma unroll
            for (int p = 0; p < 4; p++) cacc[p] = bb;
        }
        #pragma unroll
        for (int ic = 0; ic < 4; ic++) {
            const float* base = arena + ic * 1152;
            const float* wA = w2 + ((oc0    ) * 4 + ic) * 9;
            const float* wB = w2 + ((oc0 + 4) * 4 + ic) * 9;
            #pragma unroll
            for (int kh = 0; kh < 3; kh++) {
                const int r2 = 2 * oh + kh - 1;                    // real input row; -1 only if oh==0&&kh==0
                const bool zr = (kh == 0) && (oh == 0);            // row -1 -> shared zero row
                const int rc = zr ? 0 : r2;
                const int bsw = (rc >> 1) & 1;
                const float* row = zr ? (arena + 4608) : (base + rc * 36);
                const float4 qA = *(const float4*)(row + (((2 * w)     ^ bsw) << 2));
                const float4 qB = *(const float4*)(row + (((2 * w + 1) ^ bsw) << 2));
                const int sblk = (w == 0) ? bsw : ((2 * w - 1) ^ bsw);
                const float sv = row[(sblk << 2) + 3];
                float colv[9];
                colv[0] = (w == 0) ? 0.f : sv;
                colv[1] = qA.x; colv[2] = qA.y; colv[3] = qA.z; colv[4] = qA.w;
                colv[5] = qB.x; colv[6] = qB.y; colv[7] = qB.z; colv[8] = qB.w;
                #pragma unroll
                for (int kw = 0; kw < 3; kw++) {
                    const v2f wab = {wA[kh * 3 + kw], wB[kh * 3 + kw]};
                    #pragma unroll
                    for (int p = 0; p < 4; p++) {
                        const float c = colv[kw + 2 * p];
                        const v2f cs = {c, c};
                        cacc[p] = FMA2(cs, wab, cacc[p]);
                    }
                }
            }
        }
    }
    __syncthreads();

    // ---- phase B: conv2-out halo zero + store into [8][18][20] overlay; w3p/b3 -> LDS ----
    for (int i = tid; i < 544; i += 256) {
        const int ch = i / 68, j = i - ch * 68;
        if (j < 18)      arena[ch * 360 + j] = 0.f;                   // row 0
        else if (j < 36) arena[ch * 360 + 17 * 20 + (j - 18)] = 0.f;  // row 17
        else if (j < 52) arena[ch * 360 + (j - 35) * 20] = 0.f;       // col 0, rows 1..16
        else             arena[ch * 360 + (j - 51) * 20 + 17] = 0.f;  // col 17, rows 1..16
    }
    {
        const int oc0 = __builtin_amdgcn_readfirstlane(tid >> 6);
        const int oh  = lane >> 2, ow0 = (lane & 3) * 4;
        float* oA = arena + oc0 * 360       + (oh + 1) * 20 + ow0 + 1;
        float* oB = arena + (oc0 + 4) * 360 + (oh + 1) * 20 + ow0 + 1;
        oA[0] = fmaxf(cacc[0].x, 0.f); oA[1] = fmaxf(cacc[1].x, 0.f);
        oA[2] = fmaxf(cacc[2].x, 0.f); oA[3] = fmaxf(cacc[3].x, 0.f);
        oB[0] = fmaxf(cacc[0].y, 0.f); oB[1] = fmaxf(cacc[1].y, 0.f);
        oB[2] = fmaxf(cacc[2].y, 0.f); oB[3] = fmaxf(cacc[3].y, 0.f);
    }
    #pragma unroll
    for (int j = 0; j < 7; j++) {
        const int s = tid + 256 * j;
        if (s < 1600) arena[2880 + s] = wstage[j];   // [16][100] padded w3 (pad slots never read)
    }
    if (tid < 16) arena[4480 + tid] = bstage;
    __syncthreads();

    // ---- conv3 + fused 8x8 avg pool: thread = (oc, 4x4 tile), 256 threads ----
    {
        const float* w3s = arena + 2880;
        const int oc = tid >> 4, s = tid & 15;
        const int tr = (s >> 2) * 4, tc = (s & 3) * 4;
        v2f acc2[4][2];
        const float bv = w3s[1600 + oc];
        #pragma unroll
        for (int r = 0; r < 4; r++) {
            acc2[r][0] = (v2f){bv, bv};
            acc2[r][1] = (v2f){bv, bv};
        }
        #pragma unroll
        for (int ic = 0; ic < 8; ic++) {
            const float* xc = arena + ic * 360;
            const float4 wv0 = *(const float4*)(w3s + oc * 100 + ic * 12);
            const float4 wv1 = *(const float4*)(w3s + oc * 100 + ic * 12 + 4);
            const float  wv8 = w3s[oc * 100 + ic * 12 + 8];
            const float wv[9] = {wv0.x, wv0.y, wv0.z, wv0.w, wv1.x, wv1.y, wv1.z, wv1.w, wv8};
            #pragma unroll
            for (int j = 0; j < 6; j++) {
                const float* rp = xc + (tr + j) * 20 + tc;   // 16B-aligned (stride 20, tc mult of 4)
                const float4 qa = *(const float4*)(rp);
                const float4 qb = *(const float4*)(rp + 4);  // .zw in-bounds stale data, unused
                const v2f e0 = {qa.x, qa.y};
                const v2f o0 = {qa.y, qa.z};
                const v2f e1 = {qa.z, qa.w};
                const v2f o1 = {qa.w, qb.x};
                const v2f e2 = {qb.x, qb.y};
                #pragma unroll
                for (int r = 0; r < 4; r++) {
                    const int kh = j - r;                    // compile-time per (j,r)
                    if (kh >= 0 && kh < 3) {
                        const v2f w0s = {wv[kh * 3 + 0], wv[kh * 3 + 0]};
                        const v2f w1s = {wv[kh * 3 + 1], wv[kh * 3 + 1]};
                        const v2f w2s = {wv[kh * 3 + 2], wv[kh * 3 + 2]};
                        acc2[r][0] = FMA2(e0, w0s, acc2[r][0]);
                        acc2[r][0] = FMA2(o0, w1s, acc2[r][0]);
                        acc2[r][0] = FMA2(e1, w2s, acc2[r][0]);
                        acc2[r][1] = FMA2(e1, w0s, acc2[r][1]);
                        acc2[r][1] = FMA2(o1, w1s, acc2[r][1]);
                        acc2[r][1] = FMA2(e2, w2s, acc2[r][1]);
                    }
                }
            }
        }
        // relu + tile sum (r asc, c asc), quadrant reduce via shfl
        float ps = 0.f;
        #pragma unroll
        for (int r = 0; r < 4; r++) {
            ps += fmaxf(acc2[r][0].x, 0.f);
            ps += fmaxf(acc2[r][0].y, 0.f);
            ps += fmaxf(acc2[r][1].x, 0.f);
            ps += fmaxf(acc2[r][1].y, 0.f);
        }
        ps += __shfl_xor(ps, 1, 64);
        ps += __shfl_xor(ps, 4, 64);
        if ((s & 5) == 0) {
            const int ii = s >> 3, jj = (s >> 1) & 1;
            poolout[b * 64 + oc * 4 + ii * 2 + jj] = ps * (1.f / 64.f);
        }
    }
}

// ================= Kernel B: head, 4 images per block, 1024 blocks; per-wave MLP tail =========
__global__ __launch_bounds__(256)
void head_kernel(const float* __restrict__ poolin,
                 const float* __restrict__ wf, const float* __restrict__ bf,
                 const float* __restrict__ qw,
                 const float* __restrict__ wc1, const float* __restrict__ bc1,
                 const float* __restrict__ wc2, const float* __restrict__ bc2,
                 const float* __restrict__ wc3, const float* __restrict__ bc3,
                 const float* __restrict__ wc4, const float* __restrict__ bc4,
                 const float* __restrict__ wc5, const float* __restrict__ bc5,
                 float* __restrict__ out)
{
    __shared__ __align__(16) float pool_s[256];
    __shared__ __align__(16) float feats[1024];
    __shared__ __align__(16) float hbuf[4][512];   // per-wave strip: h1@0(200) h2@200(150) h3@352(100) h4@452(50)
    __shared__ float csc[56], css[56];

    const int tid  = threadIdx.x;
    const int blk  = blockIdx.x;
    const int lane = tid & 63;
    const int wv   = tid >> 6;

    pool_s[tid] = poolin[(size_t)blk * 256 + tid];
    if (tid < 56) {
        float th = qw[tid] * 0.5f;
        csc[tid] = cosf(th);
        css[tid] = sinf(th);
    }
    __syncthreads();

    // FC1: thread tid computes output tid for all 4 images; k ascending (bitwise = R17)
    {
        float acc[4];
        const float bv = bf[tid];
        #pragma unroll
        for (int e = 0; e < 4; e++) acc[e] = bv;
        const float4* wr = (const float4*)(wf + tid * 64);
        #pragma unroll
        for (int kc = 0; kc < 4; kc++) {
            float4 w0 = wr[kc * 4 + 0], w1_ = wr[kc * 4 + 1], w2_ = wr[kc * 4 + 2], w3_ = wr[kc * 4 + 3];
            #pragma unroll
            for (int e = 0; e < 4; e++) {
                const float4* pp = (const float4*)(pool_s + e * 64 + kc * 16);
                float4 p0 = pp[0], p1 = pp[1], p2 = pp[2], p3 = pp[3];
                float a = acc[e];
                a = fmaf(w0.x, p0.x, a); a = fmaf(w0.y, p0.y, a); a = fmaf(w0.z, p0.z, a); a = fmaf(w0.w, p0.w, a);
                a = fmaf(w1_.x, p1.x, a); a = fmaf(w1_.y, p1.y, a); a = fmaf(w1_.z, p1.z, a); a = fmaf(w1_.w, p1.w, a);
                a = fmaf(w2_.x, p2.x, a); a = fmaf(w2_.y, p2.y, a); a = fmaf(w2_.z, p2.z, a); a = fmaf(w2_.w, p2.w, a);
                a = fmaf(w3_.x, p3.x, a); a = fmaf(w3_.y, p3.y, a); a = fmaf(w3_.z, p3.z, a); a = fmaf(w3_.w, p3.w, a);
                acc[e] = a;
            }
        }
        #pragma unroll
        for (int e = 0; e < 4; e++) feats[e * 256 + tid] = fmaxf(acc[e], 0.f);
    }
    __syncthreads();

    // ---- quantum (verbatim); butterfly reduce leaves z in EVERY lane -> no zbuf/barrier ----
    float z;
    {
        const float* base = feats + wv * 256;
        float v0 = base[lane], v1 = base[64 + lane];
        float v2 = base[128 + lane], v3 = base[192 + lane];
        float ssq = v0 * v0 + v1 * v1 + v2 * v2 + v3 * v3;
        #pragma unroll
        for (int off = 1; off < 64; off <<= 1) ssq += __shfl_xor(ssq, off, 64);
        const float inv = 1.0f / fmaxf(sqrtf(ssq), 1e-12f);
        v0 *= inv; v1 *= inv; v2 *= inv; v3 *= inv;

        for (int l = 0; l < 7; l++) {
            {
                float c = csc[l * 8 + 0], s = css[l * 8 + 0];
                float n0 = c * v0 - s * v2, n2 = s * v0 + c * v2;
                float n1 = c * v1 - s * v3, n3 = s * v1 + c * v3;
                float c1 = csc[l * 8 + 1], s1 = css[l * 8 + 1];
                v0 = c1 * n0 - s1 * n1; v1 = s1 * n0 + c1 * n1;
                v2 = c1 * n2 - s1 * n3; v3 = s1 * n2 + c1 * n3;
            }
            #pragma unroll
            for (int q = 2; q < 8; q++) {
                const int m = 1 << (7 - q);
                const float c = csc[l * 8 + q], s = css[l * 8 + q];
                const float sgn = (lane & m) ? s : -s;
                float t0 = __shfl_xor(v0, m, 64);
                float t1 = __shfl_xor(v1, m, 64);
                float t2 = __shfl_xor(v2, m, 64);
                float t3 = __shfl_xor(v3, m, 64);
                v0 = fmaf(sgn, t0, c * v0);
                v1 = fmaf(sgn, t1, c * v1);
                v2 = fmaf(sgn, t2, c * v2);
                v3 = fmaf(sgn, t3, c * v3);
            }
            { float t = v2; v2 = v3; v3 = t; }
            v1 = __shfl_xor(v1, 32, 64);
            v3 = __shfl_xor(v3, 32, 64);
            #pragma unroll
            for (int q = 2; q < 7; q++) {
                const int mc = 1 << (7 - q), mt = 1 << (6 - q);
                float t0 = __shfl_xor(v0, mt, 64);
                float t1 = __shfl_xor(v1, mt, 64);
                float t2 = __shfl_xor(v2, mt, 64);
                float t3 = __shfl_xor(v3, mt, 64);
                if (lane & mc) { v0 = t0; v1 = t1; v2 = t2; v3 = t3; }
            }
        }
        float m0 = v0 * v0 + v1 * v1 - v2 * v2 - v3 * v3;
        #pragma unroll
        for (int off = 1; off < 64; off <<= 1) m0 += __shfl_xor(m0, off, 64);
        z = m0;                                  // all lanes hold the reduced value
    }

    // ---- per-wave MLP chain (image wv), wave-synchronous, no block barriers ----
    float* H = hbuf[wv];

    // h1 @ H[0..200): lane computes j = lane + 64t
    #pragma unroll
    for (int t = 0; t < 4; t++) {
        const int j = lane + 64 * t;
        if (j < 200) H[j] = fmaxf(fmaf(z, wc1[j], bc1[j]), 0.f);
    }
    WAVE_SYNC();

    // h2 @ H[200..350): lane computes j = lane + 64t (t<3); same per-output FMA order as R17
    #pragma unroll
    for (int t = 0; t < 3; t++) {
        const int j = lane + 64 * t;
        if (j < 150) {
            float a = bc2[j];
            const float4* wr = (const float4*)(wc2 + j * 200);
            const float4* hp = (const float4*)(H);
            #pragma unroll 5
            for (int kc = 0; kc < 25; kc++) {
                const float4 wa = wr[2 * kc], wb = wr[2 * kc + 1];
                const float4 ha = hp[2 * kc], hb = hp[2 * kc + 1];
                a = fmaf(wa.x, ha.x, a); a = fmaf(wa.y, ha.y, a); a = fmaf(wa.z, ha.z, a); a = fmaf(wa.w, ha.w, a);
                a = fmaf(wb.x, hb.x, a); a = fmaf(wb.y, hb.y, a); a = fmaf(wb.z, hb.z, a); a = fmaf(wb.w, hb.w, a);
            }
            H[200 + j] = fmaxf(a, 0.f);
        }
    }
    WAVE_SYNC();

    // h3 @ H[352..452): lane computes j = lane + 64t (t<2)
    #pragma unroll
    for (int t = 0; t < 2; t++) {
        const int j = lane + 64 * t;
        if (j < 100) {
            float a = bc3[j];
            const float2* wr = (const float2*)(wc3 + j * 150);
            const float2* hp = (const float2*)(H + 200);
            #pragma unroll 5
            for (int k = 0; k < 75; k++) {
                const float2 wa = wr[k];
                const float2 hv = hp[k];
                a = fmaf(wa.x, hv.x, fmaf(wa.y, hv.y, a));
            }
            H[352 + j] = fmaxf(a, 0.f);
        }
    }
    WAVE_SYNC();

    // h4 @ H[452..502): lane j < 50
    if (lane < 50) {
        float a = bc4[lane];
        const float4* wr = (const float4*)(wc4 + lane * 100);
        const float4* hp = (const float4*)(H + 352);
        #pragma unroll 5
        for (int kc = 0; kc < 25; kc++) {
            const float4 wa = wr[kc];
            const float4 hv = hp[kc];
            a = fmaf(wa.x, hv.x, a); a = fmaf(wa.y, hv.y, a);
            a = fmaf(wa.z, hv.z, a); a = fmaf(wa.w, hv.w, a);
        }
        H[452 + lane] = fmaxf(a, 0.f);
    }
    WAVE_SYNC();

    // out: lane 0, same serial 50-dot as R17's tid<4 path
    if (lane == 0) {
        float a = bc5[0];
        const float2* wr = (const float2*)wc5;
        const float2* hp = (const float2*)(H + 452);
        #pragma unroll
        for (int k = 0; k < 25; k++) {
            const float2 wa = wr[k];
            const float2 hv = hp[k];
            a = fmaf(wa.x, hv.x, fmaf(wa.y, hv.y, a));
        }
        out[blk * 4 + wv] = 1.0f / (1.0f + expf(-a));
    }
}

extern "C" void kernel_launch(void* const* d_in, const int* in_sizes, int n_in,
                              void* d_out, int out_size, void* d_ws, size_t ws_size,
                              hipStream_t stream) {
    const float* x   = (const float*)d_in[0];
    const float* w1  = (const float*)d_in[1];
    const float* b1  = (const float*)d_in[2];
    const float* w2  = (const float*)d_in[3];
    const float* b2  = (const float*)d_in[4];
    const float* w3  = (const float*)d_in[5];
    const float* b3  = (const float*)d_in[6];
    const float* wf  = (const float*)d_in[7];
    const float* bf  = (const float*)d_in[8];
    const float* qw  = (const float*)d_in[9];
    const float* wc1 = (const float*)d_in[10];
    const float* bc1 = (const float*)d_in[11];
    const float* wc2 = (const float*)d_in[12];
    const float* bc2 = (const float*)d_in[13];
    const float* wc3 = (const float*)d_in[14];
    const float* bc3 = (const float*)d_in[15];
    const float* wc4 = (const float*)d_in[16];
    const float* bc4 = (const float*)d_in[17];
    const float* wc5 = (const float*)d_in[18];
    const float* bc5 = (const float*)d_in[19];
    float* out = (float*)d_out;

    float* poolbuf = (float*)d_ws;   // 4096*64 floats = 1 MB

    convpool_kernel<<<4096, 256, 0, stream>>>(x, w1, b1, w2, b2, w3, b3, poolbuf);
    head_kernel<<<1024, 256, 0, stream>>>(poolbuf, wf, bf, qw,
                                          wc1, bc1, wc2, bc2, wc3, bc3,
                                          wc4, bc4, wc5, bc5, out);
}

// Round 12
// 211.297 us; speedup vs baseline: 1.1337x; 1.1337x over previous
//
#include <hip/hip_runtime.h>
#include <math.h>

typedef float v2f __attribute__((ext_vector_type(2)));
#define FMA2(a, b, c) __builtin_elementwise_fma((a), (b), (c))

// ================= Kernel A: conv1+conv2+conv3+pool fused, one block per image =================
// R22 = R20 (best measured: 209.6us total) + head latency cuts. convpool byte-identical
//  (62us anchor). Head (4 img/1024 blocks, lockstep MLP for 4x weight-load reuse -- R21's
//  per-wave tail lost that reuse and regressed 48->83us):
//   - h3 unroll 5 -> 15 (15 -> 5 serial L2-load groups on the longest MLP chain)
//   - wc1/bc1 prefetched to regs pre-quantum (h1 cold-start hidden)
//   - wc4 first float4 prefetched post-h2-barrier (hidden under h3)
//  Per-output FMA order unchanged -> bitwise same result.
__global__ __launch_bounds__(256, 8)
void convpool_kernel(const float* __restrict__ x,
                     const float* __restrict__ w1, const float* __restrict__ b1,
                     const float* __restrict__ w2, const float* __restrict__ b2,
                     const float* __restrict__ w3, const float* __restrict__ b3,
                     float* __restrict__ poolout)
{
    __shared__ __align__(16) float arena[4648];   // phase A: conv1-out [4][32][36] + zero row @4608
                                                  // phase B: conv2-out [8][18][20] @0 + w3p [16][100] @2880 + b3 @4480
    const int tid  = threadIdx.x;
    const int b    = blockIdx.x;
    const int lane = tid & 63;

    // ---- issue w3 (padded [16][8][12], oc-stride 100) + b3 loads into registers ----
    float wstage[7];
    #pragma unroll
    for (int j = 0; j < 7; j++) {
        const int s  = tid + 256 * j;          // 0..1791, valid slots < 1600
        const int oc = s / 100;
        const int r  = s - oc * 100;
        const int ic = r / 12;
        const int k  = r - ic * 12;
        wstage[j] = (s < 1600 && r < 96 && k < 9) ? w3[oc * 72 + ic * 9 + k] : 0.f;
    }
    const float bstage = (tid < 16) ? b3[tid] : 0.f;

    // ---- zero row for conv2's row -1 (ordered by the post-conv1 barrier) ----
    if (tid < 40) arena[4608 + tid] = 0.f;

    // ---- conv1: k5 s2 p2, oc-packed: aP[px][{oc0,oc1}|{oc2,oc3}] ----
    {
        const float* xb = x + (size_t)b * 4096;
        const int oh  = tid >> 3;              // 0..31
        const int ow  = tid & 7;               // output block index (4 cols)
        const int ow0 = ow * 4;
        const int c0  = ow0 * 2 - 2;
        const bool cmL = (ow == 0);
        const bool cmR = (ow == 7);
        v2f aP[4][2];                           // [px][ocpair]
        {
            const v2f b01 = {b1[0], b1[1]};
            const v2f b23 = {b1[2], b1[3]};
            #pragma unroll
            for (int p = 0; p < 4; p++) { aP[p][0] = b01; aP[p][1] = b23; }
        }
        #pragma unroll
        for (int kh = 0; kh < 5; kh++) {
            const int ih = oh * 2 - 2 + kh;
            if (ih >= 0 && ih < 64) {
                const float* row = xb + ih * 64;
                float colv[11];
                {   // edges: clamped addresses, masked values
                    float v0 = row[cmL ? 0 : c0];
                    float v1 = row[cmL ? 0 : c0 + 1];
                    float vA = row[cmR ? 63 : c0 + 10];
                    colv[0]  = cmL ? 0.f : v0;
                    colv[1]  = cmL ? 0.f : v1;
                    colv[10] = cmR ? 0.f : vA;
                }
                {   // middle 8 taps: two aligned dwordx4 (c0+2 = ow*8)
                    const float4 m0 = *(const float4*)(row + c0 + 2);
                    const float4 m1 = *(const float4*)(row + c0 + 6);
                    colv[2] = m0.x; colv[3] = m0.y; colv[4] = m0.z; colv[5] = m0.w;
                    colv[6] = m1.x; colv[7] = m1.y; colv[8] = m1.z; colv[9] = m1.w;
                }
                #pragma unroll
                for (int kw = 0; kw < 5; kw++) {
                    const v2f w01 = {w1[kh * 5 + kw],      w1[25 + kh * 5 + kw]};
                    const v2f w23 = {w1[50 + kh * 5 + kw], w1[75 + kh * 5 + kw]};
                    #pragma unroll
                    for (int p = 0; p < 4; p++) {
                        const float c = colv[kw + 2 * p];
                        const v2f cs = {c, c};          // op_sel broadcast, no movs
                        aP[p][0] = FMA2(cs, w01, aP[p][0]);
                        aP[p][1] = FMA2(cs, w23, aP[p][1]);
                    }
                }
            }
        }
        // store: [4][32][36], block (ow ^ ((oh>>1)&1)) -> conflict-free b128
        const int bsw1 = (oh >> 1) & 1;
        float* obase = arena + oh * 36 + ((ow ^ bsw1) << 2);
        {
            float4 v;
            v.x = fmaxf(aP[0][0].x, 0.f); v.y = fmaxf(aP[1][0].x, 0.f);
            v.z = fmaxf(aP[2][0].x, 0.f); v.w = fmaxf(aP[3][0].x, 0.f);
            *(float4*)(obase) = v;
            v.x = fmaxf(aP[0][0].y, 0.f); v.y = fmaxf(aP[1][0].y, 0.f);
            v.z = fmaxf(aP[2][0].y, 0.f); v.w = fmaxf(aP[3][0].y, 0.f);
            *(float4*)(obase + 1152) = v;
            v.x = fmaxf(aP[0][1].x, 0.f); v.y = fmaxf(aP[1][1].x, 0.f);
            v.z = fmaxf(aP[2][1].x, 0.f); v.w = fmaxf(aP[3][1].x, 0.f);
            *(float4*)(obase + 2304) = v;
            v.x = fmaxf(aP[0][1].y, 0.f); v.y = fmaxf(aP[1][1].y, 0.f);
            v.z = fmaxf(aP[2][1].y, 0.f); v.w = fmaxf(aP[3][1].y, 0.f);
            *(float4*)(obase + 3456) = v;
        }
    }
    __syncthreads();

    // ---- conv2: k3 s2 p1, oc-packed acc[px] = {oc0, oc0+4} ----
    v2f cacc[4];
    {
        const int oc0 = __builtin_amdgcn_readfirstlane(tid >> 6);   // 0..3, wave-uniform
        const int oh  = lane >> 2;             // output row 0..15
        const int w   = lane & 3;              // output col block (4 cols)
        {
            const v2f bb = {b2[oc0], b2[oc0 + 4]};
            #pragma unroll
            for (int p = 0; p < 4; p++) cacc[p] = bb;
        }
        #pragma unroll
        for (int ic = 0; ic < 4; ic++) {
            const float* base = arena + ic * 1152;
            const float* wA = w2 + ((oc0    ) * 4 + ic) * 9;
            const float* wB = w2 + ((oc0 + 4) * 4 + ic) * 9;
            #pragma unroll
            for (int kh = 0; kh < 3; kh++) {
                const int r2 = 2 * oh + kh - 1;                    // real input row; -1 only if oh==0&&kh==0
                const bool zr = (kh == 0) && (oh == 0);            // row -1 -> shared zero row
                const int rc = zr ? 0 : r2;
                const int bsw = (rc >> 1) & 1;
                const float* row = zr ? (arena + 4608) : (base + rc * 36);
                const float4 qA = *(const float4*)(row + (((2 * w)     ^ bsw) << 2));
                const float4 qB = *(const float4*)(row + (((2 * w + 1) ^ bsw) << 2));
                const int sblk = (w == 0) ? bsw : ((2 * w - 1) ^ bsw);
                const float sv = row[(sblk << 2) + 3];
                float colv[9];
                colv[0] = (w == 0) ? 0.f : sv;
                colv[1] = qA.x; colv[2] = qA.y; colv[3] = qA.z; colv[4] = qA.w;
                colv[5] = qB.x; colv[6] = qB.y; colv[7] = qB.z; colv[8] = qB.w;
                #pragma unroll
                for (int kw = 0; kw < 3; kw++) {
                    const v2f wab = {wA[kh * 3 + kw], wB[kh * 3 + kw]};
                    #pragma unroll
                    for (int p = 0; p < 4; p++) {
                        const float c = colv[kw + 2 * p];
                        const v2f cs = {c, c};
                        cacc[p] = FMA2(cs, wab, cacc[p]);
                    }
                }
            }
        }
    }
    __syncthreads();

    // ---- phase B: conv2-out halo zero + store into [8][18][20] overlay; w3p/b3 -> LDS ----
    for (int i = tid; i < 544; i += 256) {
        const int ch = i / 68, j = i - ch * 68;
        if (j < 18)      arena[ch * 360 + j] = 0.f;                   // row 0
        else if (j < 36) arena[ch * 360 + 17 * 20 + (j - 18)] = 0.f;  // row 17
        else if (j < 52) arena[ch * 360 + (j - 35) * 20] = 0.f;       // col 0, rows 1..16
        else             arena[ch * 360 + (j - 51) * 20 + 17] = 0.f;  // col 17, rows 1..16
    }
    {
        const int oc0 = __builtin_amdgcn_readfirstlane(tid >> 6);
        const int oh  = lane >> 2, ow0 = (lane & 3) * 4;
        float* oA = arena + oc0 * 360       + (oh + 1) * 20 + ow0 + 1;
        float* oB = arena + (oc0 + 4) * 360 + (oh + 1) * 20 + ow0 + 1;
        oA[0] = fmaxf(cacc[0].x, 0.f); oA[1] = fmaxf(cacc[1].x, 0.f);
        oA[2] = fmaxf(cacc[2].x, 0.f); oA[3] = fmaxf(cacc[3].x, 0.f);
        oB[0] = fmaxf(cacc[0].y, 0.f); oB[1] = fmaxf(cacc[1].y, 0.f);
        oB[2] = fmaxf(cacc[2].y, 0.f); oB[3] = fmaxf(cacc[3].y, 0.f);
    }
    #pragma unroll
    for (int j = 0; j < 7; j++) {
        const int s = tid + 256 * j;
        if (s < 1600) arena[2880 + s] = wstage[j];   // [16][100] padded w3 (pad slots never read)
    }
    if (tid < 16) arena[4480 + tid] = bstage;
    __syncthreads();

    // ---- conv3 + fused 8x8 avg pool: thread = (oc, 4x4 tile), 256 threads ----
    {
        const float* w3s = arena + 2880;
        const int oc = tid >> 4, s = tid & 15;
        const int tr = (s >> 2) * 4, tc = (s & 3) * 4;
        v2f acc2[4][2];
        const float bv = w3s[1600 + oc];
        #pragma unroll
        for (int r = 0; r < 4; r++) {
            acc2[r][0] = (v2f){bv, bv};
            acc2[r][1] = (v2f){bv, bv};
        }
        #pragma unroll
        for (int ic = 0; ic < 8; ic++) {
            const float* xc = arena + ic * 360;
            const float4 wv0 = *(const float4*)(w3s + oc * 100 + ic * 12);
            const float4 wv1 = *(const float4*)(w3s + oc * 100 + ic * 12 + 4);
            const float  wv8 = w3s[oc * 100 + ic * 12 + 8];
            const float wv[9] = {wv0.x, wv0.y, wv0.z, wv0.w, wv1.x, wv1.y, wv1.z, wv1.w, wv8};
            #pragma unroll
            for (int j = 0; j < 6; j++) {
                const float* rp = xc + (tr + j) * 20 + tc;   // 16B-aligned (stride 20, tc mult of 4)
                const float4 qa = *(const float4*)(rp);
                const float4 qb = *(const float4*)(rp + 4);  // .zw in-bounds stale data, unused
                const v2f e0 = {qa.x, qa.y};
                const v2f o0 = {qa.y, qa.z};
                const v2f e1 = {qa.z, qa.w};
                const v2f o1 = {qa.w, qb.x};
                const v2f e2 = {qb.x, qb.y};
                #pragma unroll
                for (int r = 0; r < 4; r++) {
                    const int kh = j - r;                    // compile-time per (j,r)
                    if (kh >= 0 && kh < 3) {
                        const v2f w0s = {wv[kh * 3 + 0], wv[kh * 3 + 0]};
                        const v2f w1s = {wv[kh * 3 + 1], wv[kh * 3 + 1]};
                        const v2f w2s = {wv[kh * 3 + 2], wv[kh * 3 + 2]};
                        acc2[r][0] = FMA2(e0, w0s, acc2[r][0]);
                        acc2[r][0] = FMA2(o0, w1s, acc2[r][0]);
                        acc2[r][0] = FMA2(e1, w2s, acc2[r][0]);
                        acc2[r][1] = FMA2(e1, w0s, acc2[r][1]);
                        acc2[r][1] = FMA2(o1, w1s, acc2[r][1]);
                        acc2[r][1] = FMA2(e2, w2s, acc2[r][1]);
                    }
                }
            }
        }
        // relu + tile sum (r asc, c asc), quadrant reduce via shfl
        float ps = 0.f;
        #pragma unroll
        for (int r = 0; r < 4; r++) {
            ps += fmaxf(acc2[r][0].x, 0.f);
            ps += fmaxf(acc2[r][0].y, 0.f);
            ps += fmaxf(acc2[r][1].x, 0.f);
            ps += fmaxf(acc2[r][1].y, 0.f);
        }
        ps += __shfl_xor(ps, 1, 64);
        ps += __shfl_xor(ps, 4, 64);
        if ((s & 5) == 0) {
            const int ii = s >> 3, jj = (s >> 1) & 1;
            poolout[b * 64 + oc * 4 + ii * 2 + jj] = ps * (1.f / 64.f);
        }
    }
}

// ================= Kernel B: head, 4 images per block, 1024 blocks =================
__global__ __launch_bounds__(256)
void head_kernel(const float* __restrict__ poolin,
                 const float* __restrict__ wf, const float* __restrict__ bf,
                 const float* __restrict__ qw,
                 const float* __restrict__ wc1, const float* __restrict__ bc1,
                 const float* __restrict__ wc2, const float* __restrict__ bc2,
                 const float* __restrict__ wc3, const float* __restrict__ bc3,
                 const float* __restrict__ wc4, const float* __restrict__ bc4,
                 const float* __restrict__ wc5, const float* __restrict__ bc5,
                 float* __restrict__ out)
{
    __shared__ __align__(16) float pool_s[256];
    __shared__ __align__(16) float feats[1024];
    __shared__ __align__(16) float h1[800];
    __shared__ __align__(16) float h2[600];
    __shared__ __align__(16) float h3[400];
    __shared__ __align__(16) float h4[200];
    __shared__ float zbuf[4];
    __shared__ float csc[56], css[56];

    const int tid  = threadIdx.x;
    const int blk  = blockIdx.x;
    const int lane = tid & 63;
    const int wv   = tid >> 6;

    pool_s[tid] = poolin[(size_t)blk * 256 + tid];
    if (tid < 56) {
        float th = qw[tid] * 0.5f;
        csc[tid] = cosf(th);
        css[tid] = sinf(th);
    }
    __syncthreads();

    {
        float acc[4];
        const float bv = bf[tid];
        #pragma unroll
        for (int e = 0; e < 4; e++) acc[e] = bv;
        const float4* wr = (const float4*)(wf + tid * 64);
        #pragma unroll
        for (int kc = 0; kc < 4; kc++) {
            float4 w0 = wr[kc * 4 + 0], w1_ = wr[kc * 4 + 1], w2_ = wr[kc * 4 + 2], w3_ = wr[kc * 4 + 3];
            #pragma unroll
            for (int e = 0; e < 4; e++) {
                const float4* pp = (const float4*)(pool_s + e * 64 + kc * 16);
                float4 p0 = pp[0], p1 = pp[1], p2 = pp[2], p3 = pp[3];
                float a = acc[e];
                a = fmaf(w0.x, p0.x, a); a = fmaf(w0.y, p0.y, a); a = fmaf(w0.z, p0.z, a); a = fmaf(w0.w, p0.w, a);
                a = fmaf(w1_.x, p1.x, a); a = fmaf(w1_.y, p1.y, a); a = fmaf(w1_.z, p1.z, a); a = fmaf(w1_.w, p1.w, a);
                a = fmaf(w2_.x, p2.x, a); a = fmaf(w2_.y, p2.y, a); a = fmaf(w2_.z, p2.z, a); a = fmaf(w2_.w, p2.w, a);
                a = fmaf(w3_.x, p3.x, a); a = fmaf(w3_.y, p3.y, a); a = fmaf(w3_.z, p3.z, a); a = fmaf(w3_.w, p3.w, a);
                acc[e] = a;
            }
        }
        #pragma unroll
        for (int e = 0; e < 4; e++) feats[e * 256 + tid] = fmaxf(acc[e], 0.f);
    }

    // prefetches hidden under quantum: h2's first weight pair + h1's weight/bias
    float4 pw0, pw1;
    float pwc1, pbc1;
    if (tid < 150) {
        const float4* wr2 = (const float4*)(wc2 + tid * 200);
        pw0 = wr2[0];
        pw1 = wr2[1];
    }
    if (tid < 200) {
        pwc1 = wc1[tid];
        pbc1 = bc1[tid];
    }
    __syncthreads();

    {
        const float* base = feats + wv * 256;
        float v0 = base[lane], v1 = base[64 + lane];
        float v2 = base[128 + lane], v3 = base[192 + lane];
        float ssq = v0 * v0 + v1 * v1 + v2 * v2 + v3 * v3;
        #pragma unroll
        for (int off = 1; off < 64; off <<= 1) ssq += __shfl_xor(ssq, off, 64);
        const float inv = 1.0f / fmaxf(sqrtf(ssq), 1e-12f);
        v0 *= inv; v1 *= inv; v2 *= inv; v3 *= inv;

        for (int l = 0; l < 7; l++) {
            {
                float c = csc[l * 8 + 0], s = css[l * 8 + 0];
                float n0 = c * v0 - s * v2, n2 = s * v0 + c * v2;
                float n1 = c * v1 - s * v3, n3 = s * v1 + c * v3;
                float c1 = csc[l * 8 + 1], s1 = css[l * 8 + 1];
                v0 = c1 * n0 - s1 * n1; v1 = s1 * n0 + c1 * n1;
                v2 = c1 * n2 - s1 * n3; v3 = s1 * n2 + c1 * n3;
            }
            #pragma unroll
            for (int q = 2; q < 8; q++) {
                const int m = 1 << (7 - q);
                const float c = csc[l * 8 + q], s = css[l * 8 + q];
                const float sgn = (lane & m) ? s : -s;
                float t0 = __shfl_xor(v0, m, 64);
                float t1 = __shfl_xor(v1, m, 64);
                float t2 = __shfl_xor(v2, m, 64);
                float t3 = __shfl_xor(v3, m, 64);
                v0 = fmaf(sgn, t0, c * v0);
                v1 = fmaf(sgn, t1, c * v1);
                v2 = fmaf(sgn, t2, c * v2);
                v3 = fmaf(sgn, t3, c * v3);
            }
            { float t = v2; v2 = v3; v3 = t; }
            v1 = __shfl_xor(v1, 32, 64);
            v3 = __shfl_xor(v3, 32, 64);
            #pragma unroll
            for (int q = 2; q < 7; q++) {
                const int mc = 1 << (7 - q), mt = 1 << (6 - q);
                float t0 = __shfl_xor(v0, mt, 64);
                float t1 = __shfl_xor(v1, mt, 64);
                float t2 = __shfl_xor(v2, mt, 64);
                float t3 = __shfl_xor(v3, mt, 64);
                if (lane & mc) { v0 = t0; v1 = t1; v2 = t2; v3 = t3; }
            }
        }
        float m0 = v0 * v0 + v1 * v1 - v2 * v2 - v3 * v3;
        #pragma unroll
        for (int off = 1; off < 64; off <<= 1) m0 += __shfl_xor(m0, off, 64);
        if (lane == 0) zbuf[wv] = m0;
    }
    __syncthreads();

    if (tid < 200) {
        #pragma unroll
        for (int e = 0; e < 4; e++) h1[e * 200 + tid] = fmaxf(fmaf(zbuf[e], pwc1, pbc1), 0.f);
    }
    __syncthreads();
    if (tid < 150) {
        float acc[4];
        const float bv = bc2[tid];
        #pragma unroll
        for (int e = 0; e < 4; e++) acc[e] = bv;
        const float4* wr = (const float4*)(wc2 + tid * 200);
        {   // kc = 0: prefetched pair, same FMA order
            const float4 wa = pw0, wb = pw1;
            #pragma unroll
            for (int e = 0; e < 4; e++) {
                const float4* hp = (const float4*)(h1 + e * 200);
                float4 ha = hp[0], hb = hp[1];
                float a = acc[e];
                a = fmaf(wa.x, ha.x, a); a = fmaf(wa.y, ha.y, a); a = fmaf(wa.z, ha.z, a); a = fmaf(wa.w, ha.w, a);
                a = fmaf(wb.x, hb.x, a); a = fmaf(wb.y, hb.y, a); a = fmaf(wb.z, hb.z, a); a = fmaf(wb.w, hb.w, a);
                acc[e] = a;
            }
        }
        #pragma unroll 4
        for (int kc = 1; kc < 25; kc++) {
            float4 wa = wr[2 * kc], wb = wr[2 * kc + 1];
            #pragma unroll
            for (int e = 0; e < 4; e++) {
                const float4* hp = (const float4*)(h1 + e * 200) + 2 * kc;
                float4 ha = hp[0], hb = hp[1];
                float a = acc[e];
                a = fmaf(wa.x, ha.x, a); a = fmaf(wa.y, ha.y, a); a = fmaf(wa.z, ha.z, a); a = fmaf(wa.w, ha.w, a);
                a = fmaf(wb.x, hb.x, a); a = fmaf(wb.y, hb.y, a); a = fmaf(wb.z, hb.z, a); a = fmaf(wb.w, hb.w, a);
                acc[e] = a;
            }
        }
        #pragma unroll
        for (int e = 0; e < 4; e++) h2[e * 150 + tid] = fmaxf(acc[e], 0.f);
    }

    // prefetch wc4's first float4 (hidden under h3; drained at the post-h3 barrier)
    float4 pw4;
    if (tid < 50) pw4 = *(const float4*)(wc4 + tid * 100);
    __syncthreads();

    if (tid < 100) {
        float acc[4];
        const float bv = bc3[tid];
        #pragma unroll
        for (int e = 0; e < 4; e++) acc[e] = bv;
        const float2* wr = (const float2*)(wc3 + tid * 150);
        #pragma unroll 15
        for (int k = 0; k < 75; k++) {
            float2 wa = wr[k];
            #pragma unroll
            for (int e = 0; e < 4; e++) {
                float2 hv = ((const float2*)(h2 + e * 150))[k];
                acc[e] = fmaf(wa.x, hv.x, fmaf(wa.y, hv.y, acc[e]));
            }
        }
        #pragma unroll
        for (int e = 0; e < 4; e++) h3[e * 100 + tid] = fmaxf(acc[e], 0.f);
    }
    __syncthreads();
    if (tid < 50) {
        float acc[4];
        const float bv = bc4[tid];
        #pragma unroll
        for (int e = 0; e < 4; e++) acc[e] = bv;
        const float4* wr = (const float4*)(wc4 + tid * 100);
        {   // kc = 0: prefetched, same FMA order
            const float4 wa = pw4;
            #pragma unroll
            for (int e = 0; e < 4; e++) {
                float4 hv = ((const float4*)(h3 + e * 100))[0];
                float a = acc[e];
                a = fmaf(wa.x, hv.x, a); a = fmaf(wa.y, hv.y, a);
                a = fmaf(wa.z, hv.z, a); a = fmaf(wa.w, hv.w, a);
                acc[e] = a;
            }
        }
        #pragma unroll 4
        for (int kc = 1; kc < 25; kc++) {
            float4 wa = wr[kc];
            #pragma unroll
            for (int e = 0; e < 4; e++) {
                float4 hv = ((const float4*)(h3 + e * 100))[kc];
                float a = acc[e];
                a = fmaf(wa.x, hv.x, a); a = fmaf(wa.y, hv.y, a);
                a = fmaf(wa.z, hv.z, a); a = fmaf(wa.w, hv.w, a);
                acc[e] = a;
            }
        }
        #pragma unroll
        for (int e = 0; e < 4; e++) h4[e * 50 + tid] = fmaxf(acc[e], 0.f);
    }
    __syncthreads();
    if (tid < 4) {
        float acc = bc5[0];
        const float2* wr = (const float2*)wc5;
        #pragma unroll
        for (int k = 0; k < 25; k++) {
            float2 wa = wr[k];
            float2 hv = ((const float2*)(h4 + tid * 50))[k];
            acc = fmaf(wa.x, hv.x, fmaf(wa.y, hv.y, acc));
        }
        out[blk * 4 + tid] = 1.0f / (1.0f + expf(-acc));
    }
}

extern "C" void kernel_launch(void* const* d_in, const int* in_sizes, int n_in,
                              void* d_out, int out_size, void* d_ws, size_t ws_size,
                              hipStream_t stream) {
    const float* x   = (const float*)d_in[0];
    const float* w1  = (const float*)d_in[1];
    const float* b1  = (const float*)d_in[2];
    const float* w2  = (const float*)d_in[3];
    const float* b2  = (const float*)d_in[4];
    const float* w3  = (const float*)d_in[5];
    const float* b3  = (const float*)d_in[6];
    const float* wf  = (const float*)d_in[7];
    const float* bf  = (const float*)d_in[8];
    const float* qw  = (const float*)d_in[9];
    const float* wc1 = (const float*)d_in[10];
    const float* bc1 = (const float*)d_in[11];
    const float* wc2 = (const float*)d_in[12];
    const float* bc2 = (const float*)d_in[13];
    const float* wc3 = (const float*)d_in[14];
    const float* bc3 = (const float*)d_in[15];
    const float* wc4 = (const float*)d_in[16];
    const float* bc4 = (const float*)d_in[17];
    const float* wc5 = (const float*)d_in[18];
    const float* bc5 = (const float*)d_in[19];
    float* out = (float*)d_out;

    float* poolbuf = (float*)d_ws;   // 4096*64 floats = 1 MB

    convpool_kernel<<<4096, 256, 0, stream>>>(x, w1, b1, w2, b2, w3, b3, poolbuf);
    head_kernel<<<1024, 256, 0, stream>>>(poolbuf, wf, bf, qw,
                                          wc1, bc1, wc2, bc2, wc3, bc3,
                                          wc4, bc4, wc5, bc5, out);
}

// Round 13
// 202.227 us; speedup vs baseline: 1.1845x; 1.0449x over previous
//
#include <hip/hip_runtime.h>
#include <math.h>

typedef float v2f __attribute__((ext_vector_type(2)));
#define FMA2(a, b, c) __builtin_elementwise_fma((a), (b), (c))

// xor-lane exchange with the cheapest transport per mask (bitwise-identical to __shfl_xor):
//  m=1,2  -> DPP quad_perm (VALU, no DS round trip)   [ctrl 0xB1 = sel{1,0,3,2}, 0x4E = sel{2,3,0,1}]
//  m=4,8,16 -> ds_swizzle BitMode xor (single DS op)  [0x101F / 0x201F / 0x401F per ISA doc]
//  m=32   -> __shfl_xor (crosses 32-lane halves)
__device__ __forceinline__ float xorlane(float v, const int m) {
    switch (m) {
    case 1:  return __int_as_float(__builtin_amdgcn_update_dpp(0, __float_as_int(v), 0xB1, 0xF, 0xF, true));
    case 2:  return __int_as_float(__builtin_amdgcn_update_dpp(0, __float_as_int(v), 0x4E, 0xF, 0xF, true));
    case 4:  return __int_as_float(__builtin_amdgcn_ds_swizzle(__float_as_int(v), 0x101F));
    case 8:  return __int_as_float(__builtin_amdgcn_ds_swizzle(__float_as_int(v), 0x201F));
    case 16: return __int_as_float(__builtin_amdgcn_ds_swizzle(__float_as_int(v), 0x401F));
    default: return __shfl_xor(v, m, 64);
    }
}

// ================= Kernel A: conv1+conv2+conv3+pool fused, one block per image =================
// R23 = R20 (measured best: 209.6us) with quantum/reduce cross-lane transport swapped to
//  DPP/ds_swizzle where the mask allows (values identical -> bitwise same result).
//  convpool byte-identical except the two pool-reduce shfls use xorlane (xor1 DPP, xor4 swizzle).
__global__ __launch_bounds__(256, 8)
void convpool_kernel(const float* __restrict__ x,
                     const float* __restrict__ w1, const float* __restrict__ b1,
                     const float* __restrict__ w2, const float* __restrict__ b2,
                     const float* __restrict__ w3, const float* __restrict__ b3,
                     float* __restrict__ poolout)
{
    __shared__ __align__(16) float arena[4648];   // phase A: conv1-out [4][32][36] + zero row @4608
                                                  // phase B: conv2-out [8][18][20] @0 + w3p [16][100] @2880 + b3 @4480
    const int tid  = threadIdx.x;
    const int b    = blockIdx.x;
    const int lane = tid & 63;

    // ---- issue w3 (padded [16][8][12], oc-stride 100) + b3 loads into registers ----
    float wstage[7];
    #pragma unroll
    for (int j = 0; j < 7; j++) {
        const int s  = tid + 256 * j;          // 0..1791, valid slots < 1600
        const int oc = s / 100;
        const int r  = s - oc * 100;
        const int ic = r / 12;
        const int k  = r - ic * 12;
        wstage[j] = (s < 1600 && r < 96 && k < 9) ? w3[oc * 72 + ic * 9 + k] : 0.f;
    }
    const float bstage = (tid < 16) ? b3[tid] : 0.f;

    // ---- zero row for conv2's row -1 (ordered by the post-conv1 barrier) ----
    if (tid < 40) arena[4608 + tid] = 0.f;

    // ---- conv1: k5 s2 p2, oc-packed: aP[px][{oc0,oc1}|{oc2,oc3}] ----
    {
        const float* xb = x + (size_t)b * 4096;
        const int oh  = tid >> 3;              // 0..31
        const int ow  = tid & 7;               // output block index (4 cols)
        const int ow0 = ow * 4;
        const int c0  = ow0 * 2 - 2;
        const bool cmL = (ow == 0);
        const bool cmR = (ow == 7);
        v2f aP[4][2];                           // [px][ocpair]
        {
            const v2f b01 = {b1[0], b1[1]};
            const v2f b23 = {b1[2], b1[3]};
            #pragma unroll
            for (int p = 0; p < 4; p++) { aP[p][0] = b01; aP[p][1] = b23; }
        }
        #pragma unroll
        for (int kh = 0; kh < 5; kh++) {
            const int ih = oh * 2 - 2 + kh;
            if (ih >= 0 && ih < 64) {
                const float* row = xb + ih * 64;
                float colv[11];
                {   // edges: clamped addresses, masked values
                    float v0 = row[cmL ? 0 : c0];
                    float v1 = row[cmL ? 0 : c0 + 1];
                    float vA = row[cmR ? 63 : c0 + 10];
                    colv[0]  = cmL ? 0.f : v0;
                    colv[1]  = cmL ? 0.f : v1;
                    colv[10] = cmR ? 0.f : vA;
                }
                {   // middle 8 taps: two aligned dwordx4 (c0+2 = ow*8)
                    const float4 m0 = *(const float4*)(row + c0 + 2);
                    const float4 m1 = *(const float4*)(row + c0 + 6);
                    colv[2] = m0.x; colv[3] = m0.y; colv[4] = m0.z; colv[5] = m0.w;
                    colv[6] = m1.x; colv[7] = m1.y; colv[8] = m1.z; colv[9] = m1.w;
                }
                #pragma unroll
                for (int kw = 0; kw < 5; kw++) {
                    const v2f w01 = {w1[kh * 5 + kw],      w1[25 + kh * 5 + kw]};
                    const v2f w23 = {w1[50 + kh * 5 + kw], w1[75 + kh * 5 + kw]};
                    #pragma unroll
                    for (int p = 0; p < 4; p++) {
                        const float c = colv[kw + 2 * p];
                        const v2f cs = {c, c};          // op_sel broadcast, no movs
                        aP[p][0] = FMA2(cs, w01, aP[p][0]);
                        aP[p][1] = FMA2(cs, w23, aP[p][1]);
                    }
                }
            }
        }
        // store: [4][32][36], block (ow ^ ((oh>>1)&1)) -> conflict-free b128
        const int bsw1 = (oh >> 1) & 1;
        float* obase = arena + oh * 36 + ((ow ^ bsw1) << 2);
        {
            float4 v;
            v.x = fmaxf(aP[0][0].x, 0.f); v.y = fmaxf(aP[1][0].x, 0.f);
            v.z = fmaxf(aP[2][0].x, 0.f); v.w = fmaxf(aP[3][0].x, 0.f);
            *(float4*)(obase) = v;
            v.x = fmaxf(aP[0][0].y, 0.f); v.y = fmaxf(aP[1][0].y, 0.f);
            v.z = fmaxf(aP[2][0].y, 0.f); v.w = fmaxf(aP[3][0].y, 0.f);
            *(float4*)(obase + 1152) = v;
            v.x = fmaxf(aP[0][1].x, 0.f); v.y = fmaxf(aP[1][1].x, 0.f);
            v.z = fmaxf(aP[2][1].x, 0.f); v.w = fmaxf(aP[3][1].x, 0.f);
            *(float4*)(obase + 2304) = v;
            v.x = fmaxf(aP[0][1].y, 0.f); v.y = fmaxf(aP[1][1].y, 0.f);
            v.z = fmaxf(aP[2][1].y, 0.f); v.w = fmaxf(aP[3][1].y, 0.f);
            *(float4*)(obase + 3456) = v;
        }
    }
    __syncthreads();

    // ---- conv2: k3 s2 p1, oc-packed acc[px] = {oc0, oc0+4} ----
    v2f cacc[4];
    {
        const int oc0 = __builtin_amdgcn_readfirstlane(tid >> 6);   // 0..3, wave-uniform
        const int oh  = lane >> 2;             // output row 0..15
        const int w   = lane & 3;              // output col block (4 cols)
        {
            const v2f bb = {b2[oc0], b2[oc0 + 4]};
            #pragma unroll
            for (int p = 0; p < 4; p++) cacc[p] = bb;
        }
        #pragma unroll
        for (int ic = 0; ic < 4; ic++) {
            const float* base = arena + ic * 1152;
            const float* wA = w2 + ((oc0    ) * 4 + ic) * 9;
            const float* wB = w2 + ((oc0 + 4) * 4 + ic) * 9;
            #pragma unroll
            for (int kh = 0; kh < 3; kh++) {
                const int r2 = 2 * oh + kh - 1;                    // real input row; -1 only if oh==0&&kh==0
                const bool zr = (kh == 0) && (oh == 0);            // row -1 -> shared zero row
                const int rc = zr ? 0 : r2;
                const int bsw = (rc >> 1) & 1;
                const float* row = zr ? (arena + 4608) : (base + rc * 36);
                const float4 qA = *(const float4*)(row + (((2 * w)     ^ bsw) << 2));
                const float4 qB = *(const float4*)(row + (((2 * w + 1) ^ bsw) << 2));
                const int sblk = (w == 0) ? bsw : ((2 * w - 1) ^ bsw);
                const float sv = row[(sblk << 2) + 3];
                float colv[9];
                colv[0] = (w == 0) ? 0.f : sv;
                colv[1] = qA.x; colv[2] = qA.y; colv[3] = qA.z; colv[4] = qA.w;
                colv[5] = qB.x; colv[6] = qB.y; colv[7] = qB.z; colv[8] = qB.w;
                #pragma unroll
                for (int kw = 0; kw < 3; kw++) {
                    const v2f wab = {wA[kh * 3 + kw], wB[kh * 3 + kw]};
                    #pragma unroll
                    for (int p = 0; p < 4; p++) {
                        const float c = colv[kw + 2 * p];
                        const v2f cs = {c, c};
                        cacc[p] = FMA2(cs, wab, cacc[p]);
                    }
                }
            }
        }
    }
    __syncthreads();

    // ---- phase B: conv2-out halo zero + store into [8][18][20] overlay; w3p/b3 -> LDS ----
    for (int i = tid; i < 544; i += 256) {
        const int ch = i / 68, j = i - ch * 68;
        if (j < 18)      arena[ch * 360 + j] = 0.f;                   // row 0
        else if (j < 36) arena[ch * 360 + 17 * 20 + (j - 18)] = 0.f;  // row 17
        else if (j < 52) arena[ch * 360 + (j - 35) * 20] = 0.f;       // col 0, rows 1..16
        else             arena[ch * 360 + (j - 51) * 20 + 17] = 0.f;  // col 17, rows 1..16
    }
    {
        const int oc0 = __builtin_amdgcn_readfirstlane(tid >> 6);
        const int oh  = lane >> 2, ow0 = (lane & 3) * 4;
        float* oA = arena + oc0 * 360       + (oh + 1) * 20 + ow0 + 1;
        float* oB = arena + (oc0 + 4) * 360 + (oh + 1) * 20 + ow0 + 1;
        oA[0] = fmaxf(cacc[0].x, 0.f); oA[1] = fmaxf(cacc[1].x, 0.f);
        oA[2] = fmaxf(cacc[2].x, 0.f); oA[3] = fmaxf(cacc[3].x, 0.f);
        oB[0] = fmaxf(cacc[0].y, 0.f); oB[1] = fmaxf(cacc[1].y, 0.f);
        oB[2] = fmaxf(cacc[2].y, 0.f); oB[3] = fmaxf(cacc[3].y, 0.f);
    }
    #pragma unroll
    for (int j = 0; j < 7; j++) {
        const int s = tid + 256 * j;
        if (s < 1600) arena[2880 + s] = wstage[j];   // [16][100] padded w3 (pad slots never read)
    }
    if (tid < 16) arena[4480 + tid] = bstage;
    __syncthreads();

    // ---- conv3 + fused 8x8 avg pool: thread = (oc, 4x4 tile), 256 threads ----
    {
        const float* w3s = arena + 2880;
        const int oc = tid >> 4, s = tid & 15;
        const int tr = (s >> 2) * 4, tc = (s & 3) * 4;
        v2f acc2[4][2];
        const float bv = w3s[1600 + oc];
        #pragma unroll
        for (int r = 0; r < 4; r++) {
            acc2[r][0] = (v2f){bv, bv};
            acc2[r][1] = (v2f){bv, bv};
        }
        #pragma unroll
        for (int ic = 0; ic < 8; ic++) {
            const float* xc = arena + ic * 360;
            const float4 wv0 = *(const float4*)(w3s + oc * 100 + ic * 12);
            const float4 wv1 = *(const float4*)(w3s + oc * 100 + ic * 12 + 4);
            const float  wv8 = w3s[oc * 100 + ic * 12 + 8];
            const float wv[9] = {wv0.x, wv0.y, wv0.z, wv0.w, wv1.x, wv1.y, wv1.z, wv1.w, wv8};
            #pragma unroll
            for (int j = 0; j < 6; j++) {
                const float* rp = xc + (tr + j) * 20 + tc;   // 16B-aligned (stride 20, tc mult of 4)
                const float4 qa = *(const float4*)(rp);
                const float4 qb = *(const float4*)(rp + 4);  // .zw in-bounds stale data, unused
                const v2f e0 = {qa.x, qa.y};
                const v2f o0 = {qa.y, qa.z};
                const v2f e1 = {qa.z, qa.w};
                const v2f o1 = {qa.w, qb.x};
                const v2f e2 = {qb.x, qb.y};
                #pragma unroll
                for (int r = 0; r < 4; r++) {
                    const int kh = j - r;                    // compile-time per (j,r)
                    if (kh >= 0 && kh < 3) {
                        const v2f w0s = {wv[kh * 3 + 0], wv[kh * 3 + 0]};
                        const v2f w1s = {wv[kh * 3 + 1], wv[kh * 3 + 1]};
                        const v2f w2s = {wv[kh * 3 + 2], wv[kh * 3 + 2]};
                        acc2[r][0] = FMA2(e0, w0s, acc2[r][0]);
                        acc2[r][0] = FMA2(o0, w1s, acc2[r][0]);
                        acc2[r][0] = FMA2(e1, w2s, acc2[r][0]);
                        acc2[r][1] = FMA2(e1, w0s, acc2[r][1]);
                        acc2[r][1] = FMA2(o1, w1s, acc2[r][1]);
                        acc2[r][1] = FMA2(e2, w2s, acc2[r][1]);
                    }
                }
            }
        }
        // relu + tile sum (r asc, c asc), quadrant reduce via DPP/swizzle (bitwise = shfl_xor)
        float ps = 0.f;
        #pragma unroll
        for (int r = 0; r < 4; r++) {
            ps += fmaxf(acc2[r][0].x, 0.f);
            ps += fmaxf(acc2[r][0].y, 0.f);
            ps += fmaxf(acc2[r][1].x, 0.f);
            ps += fmaxf(acc2[r][1].y, 0.f);
        }
        ps += xorlane(ps, 1);
        ps += xorlane(ps, 4);
        if ((s & 5) == 0) {
            const int ii = s >> 3, jj = (s >> 1) & 1;
            poolout[b * 64 + oc * 4 + ii * 2 + jj] = ps * (1.f / 64.f);
        }
    }
}

// ================= Kernel B: head, 4 images per block, 1024 blocks =================
__global__ __launch_bounds__(256)
void head_kernel(const float* __restrict__ poolin,
                 const float* __restrict__ wf, const float* __restrict__ bf,
                 const float* __restrict__ qw,
                 const float* __restrict__ wc1, const float* __restrict__ bc1,
                 const float* __restrict__ wc2, const float* __restrict__ bc2,
                 const float* __restrict__ wc3, const float* __restrict__ bc3,
                 const float* __restrict__ wc4, const float* __restrict__ bc4,
                 const float* __restrict__ wc5, const float* __restrict__ bc5,
                 float* __restrict__ out)
{
    __shared__ __align__(16) float pool_s[256];
    __shared__ __align__(16) float feats[1024];
    __shared__ __align__(16) float h1[800];
    __shared__ __align__(16) float h2[600];
    __shared__ __align__(16) float h3[400];
    __shared__ __align__(16) float h4[200];
    __shared__ float zbuf[4];
    __shared__ float csc[56], css[56];

    const int tid  = threadIdx.x;
    const int blk  = blockIdx.x;
    const int lane = tid & 63;
    const int wv   = tid >> 6;

    pool_s[tid] = poolin[(size_t)blk * 256 + tid];
    if (tid < 56) {
        float th = qw[tid] * 0.5f;
        csc[tid] = cosf(th);
        css[tid] = sinf(th);
    }
    __syncthreads();

    {
        float acc[4];
        const float bv = bf[tid];
        #pragma unroll
        for (int e = 0; e < 4; e++) acc[e] = bv;
        const float4* wr = (const float4*)(wf + tid * 64);
        #pragma unroll
        for (int kc = 0; kc < 4; kc++) {
            float4 w0 = wr[kc * 4 + 0], w1_ = wr[kc * 4 + 1], w2_ = wr[kc * 4 + 2], w3_ = wr[kc * 4 + 3];
            #pragma unroll
            for (int e = 0; e < 4; e++) {
                const float4* pp = (const float4*)(pool_s + e * 64 + kc * 16);
                float4 p0 = pp[0], p1 = pp[1], p2 = pp[2], p3 = pp[3];
                float a = acc[e];
                a = fmaf(w0.x, p0.x, a); a = fmaf(w0.y, p0.y, a); a = fmaf(w0.z, p0.z, a); a = fmaf(w0.w, p0.w, a);
                a = fmaf(w1_.x, p1.x, a); a = fmaf(w1_.y, p1.y, a); a = fmaf(w1_.z, p1.z, a); a = fmaf(w1_.w, p1.w, a);
                a = fmaf(w2_.x, p2.x, a); a = fmaf(w2_.y, p2.y, a); a = fmaf(w2_.z, p2.z, a); a = fmaf(w2_.w, p2.w, a);
                a = fmaf(w3_.x, p3.x, a); a = fmaf(w3_.y, p3.y, a); a = fmaf(w3_.z, p3.z, a); a = fmaf(w3_.w, p3.w, a);
                acc[e] = a;
            }
        }
        #pragma unroll
        for (int e = 0; e < 4; e++) feats[e * 256 + tid] = fmaxf(acc[e], 0.f);
    }

    // prefetch h2's first weight pair (drained by the next barrier; overlaps quantum issue)
    float4 pw0, pw1;
    if (tid < 150) {
        const float4* wr2 = (const float4*)(wc2 + tid * 200);
        pw0 = wr2[0];
        pw1 = wr2[1];
    }
    __syncthreads();

    {
        const float* base = feats + wv * 256;
        float v0 = base[lane], v1 = base[64 + lane];
        float v2 = base[128 + lane], v3 = base[192 + lane];
        float ssq = v0 * v0 + v1 * v1 + v2 * v2 + v3 * v3;
        #pragma unroll
        for (int off = 1; off < 64; off <<= 1) ssq += xorlane(ssq, off);
        const float inv = 1.0f / fmaxf(sqrtf(ssq), 1e-12f);
        v0 *= inv; v1 *= inv; v2 *= inv; v3 *= inv;

        for (int l = 0; l < 7; l++) {
            {
                float c = csc[l * 8 + 0], s = css[l * 8 + 0];
                float n0 = c * v0 - s * v2, n2 = s * v0 + c * v2;
                float n1 = c * v1 - s * v3, n3 = s * v1 + c * v3;
                float c1 = csc[l * 8 + 1], s1 = css[l * 8 + 1];
                v0 = c1 * n0 - s1 * n1; v1 = s1 * n0 + c1 * n1;
                v2 = c1 * n2 - s1 * n3; v3 = s1 * n2 + c1 * n3;
            }
            #pragma unroll
            for (int q = 2; q < 8; q++) {
                const int m = 1 << (7 - q);
                const float c = csc[l * 8 + q], s = css[l * 8 + q];
                const float sgn = (lane & m) ? s : -s;
                float t0 = xorlane(v0, m);
                float t1 = xorlane(v1, m);
                float t2 = xorlane(v2, m);
                float t3 = xorlane(v3, m);
                v0 = fmaf(sgn, t0, c * v0);
                v1 = fmaf(sgn, t1, c * v1);
                v2 = fmaf(sgn, t2, c * v2);
                v3 = fmaf(sgn, t3, c * v3);
            }
            { float t = v2; v2 = v3; v3 = t; }
            v1 = xorlane(v1, 32);
            v3 = xorlane(v3, 32);
            #pragma unroll
            for (int q = 2; q < 7; q++) {
                const int mc = 1 << (7 - q), mt = 1 << (6 - q);
                float t0 = xorlane(v0, mt);
                float t1 = xorlane(v1, mt);
                float t2 = xorlane(v2, mt);
                float t3 = xorlane(v3, mt);
                if (lane & mc) { v0 = t0; v1 = t1; v2 = t2; v3 = t3; }
            }
        }
        float m0 = v0 * v0 + v1 * v1 - v2 * v2 - v3 * v3;
        #pragma unroll
        for (int off = 1; off < 64; off <<= 1) m0 += xorlane(m0, off);
        if (lane == 0) zbuf[wv] = m0;
    }
    __syncthreads();

    if (tid < 200) {
        const float w = wc1[tid], bv = bc1[tid];
        #pragma unroll
        for (int e = 0; e < 4; e++) h1[e * 200 + tid] = fmaxf(fmaf(zbuf[e], w, bv), 0.f);
    }
    __syncthreads();
    if (tid < 150) {
        float acc[4];
        const float bv = bc2[tid];
        #pragma unroll
        for (int e = 0; e < 4; e++) acc[e] = bv;
        const float4* wr = (const float4*)(wc2 + tid * 200);
        {   // kc = 0: prefetched pair, same FMA order
            const float4 wa = pw0, wb = pw1;
            #pragma unroll
            for (int e = 0; e < 4; e++) {
                const float4* hp = (const float4*)(h1 + e * 200);
                float4 ha = hp[0], hb = hp[1];
                float a = acc[e];
                a = fmaf(wa.x, ha.x, a); a = fmaf(wa.y, ha.y, a); a = fmaf(wa.z, ha.z, a); a = fmaf(wa.w, ha.w, a);
                a = fmaf(wb.x, hb.x, a); a = fmaf(wb.y, hb.y, a); a = fmaf(wb.z, hb.z, a); a = fmaf(wb.w, hb.w, a);
                acc[e] = a;
            }
        }
        #pragma unroll 4
        for (int kc = 1; kc < 25; kc++) {
            float4 wa = wr[2 * kc], wb = wr[2 * kc + 1];
            #pragma unroll
            for (int e = 0; e < 4; e++) {
                const float4* hp = (const float4*)(h1 + e * 200) + 2 * kc;
                float4 ha = hp[0], hb = hp[1];
                float a = acc[e];
                a = fmaf(wa.x, ha.x, a); a = fmaf(wa.y, ha.y, a); a = fmaf(wa.z, ha.z, a); a = fmaf(wa.w, ha.w, a);
                a = fmaf(wb.x, hb.x, a); a = fmaf(wb.y, hb.y, a); a = fmaf(wb.z, hb.z, a); a = fmaf(wb.w, hb.w, a);
                acc[e] = a;
            }
        }
        #pragma unroll
        for (int e = 0; e < 4; e++) h2[e * 150 + tid] = fmaxf(acc[e], 0.f);
    }
    __syncthreads();
    if (tid < 100) {
        float acc[4];
        const float bv = bc3[tid];
        #pragma unroll
        for (int e = 0; e < 4; e++) acc[e] = bv;
        const float2* wr = (const float2*)(wc3 + tid * 150);
        #pragma unroll 5
        for (int k = 0; k < 75; k++) {
            float2 wa = wr[k];
            #pragma unroll
            for (int e = 0; e < 4; e++) {
                float2 hv = ((const float2*)(h2 + e * 150))[k];
                acc[e] = fmaf(wa.x, hv.x, fmaf(wa.y, hv.y, acc[e]));
            }
        }
        #pragma unroll
        for (int e = 0; e < 4; e++) h3[e * 100 + tid] = fmaxf(acc[e], 0.f);
    }
    __syncthreads();
    if (tid < 50) {
        float acc[4];
        const float bv = bc4[tid];
        #pragma unroll
        for (int e = 0; e < 4; e++) acc[e] = bv;
        const float4* wr = (const float4*)(wc4 + tid * 100);
        #pragma unroll 5
        for (int kc = 0; kc < 25; kc++) {
            float4 wa = wr[kc];
            #pragma unroll
            for (int e = 0; e < 4; e++) {
                float4 hv = ((const float4*)(h3 + e * 100))[kc];
                float a = acc[e];
                a = fmaf(wa.x, hv.x, a); a = fmaf(wa.y, hv.y, a);
                a = fmaf(wa.z, hv.z, a); a = fmaf(wa.w, hv.w, a);
                acc[e] = a;
            }
        }
        #pragma unroll
        for (int e = 0; e < 4; e++) h4[e * 50 + tid] = fmaxf(acc[e], 0.f);
    }
    __syncthreads();
    if (tid < 4) {
        float acc = bc5[0];
        const float2* wr = (const float2*)wc5;
        #pragma unroll
        for (int k = 0; k < 25; k++) {
            float2 wa = wr[k];
            float2 hv = ((const float2*)(h4 + tid * 50))[k];
            acc = fmaf(wa.x, hv.x, fmaf(wa.y, hv.y, acc));
        }
        out[blk * 4 + tid] = 1.0f / (1.0f + expf(-acc));
    }
}

extern "C" void kernel_launch(void* const* d_in, const int* in_sizes, int n_in,
                              void* d_out, int out_size, void* d_ws, size_t ws_size,
                              hipStream_t stream) {
    const float* x   = (const float*)d_in[0];
    const float* w1  = (const float*)d_in[1];
    const float* b1  = (const float*)d_in[2];
    const float* w2  = (const float*)d_in[3];
    const float* b2  = (const float*)d_in[4];
    const float* w3  = (const float*)d_in[5];
    const float* b3  = (const float*)d_in[6];
    const float* wf  = (const float*)d_in[7];
    const float* bf  = (const float*)d_in[8];
    const float* qw  = (const float*)d_in[9];
    const float* wc1 = (const float*)d_in[10];
    const float* bc1 = (const float*)d_in[11];
    const float* wc2 = (const float*)d_in[12];
    const float* bc2 = (const float*)d_in[13];
    const float* wc3 = (const float*)d_in[14];
    const float* bc3 = (const float*)d_in[15];
    const float* wc4 = (const float*)d_in[16];
    const float* bc4 = (const float*)d_in[17];
    const float* wc5 = (const float*)d_in[18];
    const float* bc5 = (const float*)d_in[19];
    float* out = (float*)d_out;

    float* poolbuf = (float*)d_ws;   // 4096*64 floats = 1 MB

    convpool_kernel<<<4096, 256, 0, stream>>>(x, w1, b1, w2, b2, w3, b3, poolbuf);
    head_kernel<<<1024, 256, 0, stream>>>(poolbuf, wf, bf, qw,
                                          wc1, bc1, wc2, bc2, wc3, bc3,
                                          wc4, bc4, wc5, bc5, out);
}